// Round 20
// baseline (554.585 us; speedup 1.0000x reference)
//
#include <hip/hip_runtime.h>
#include <math.h>

#define BB 32
#define SS 2048
#define HH 1024
#define MT (BB*SS)      // 65536 rows

#define BM 256
#define BN 256
#define BK 32           // fp32 k per tile (hi/lo bf16 planes)
#define NT (HH/BK)      // 32 k-tiles
#define NCH (HH/BN)     // 4 n-chunks
#define THREADS 512     // 8 waves (2m x 4n), per-wave 128x64
// B_pre per (nch,kt) tile: 2 planes x 16 frags x 512 u16 = 16384 u16 (32KB)
#define BTILE 16384

typedef float  f32x4 __attribute__((ext_vector_type(4)));
typedef short  s16x8 __attribute__((ext_vector_type(8)));
typedef unsigned short u16;

// truncation split: x ~= hi + lo, |x - hi - lo| <= 2^-16 |x|
__device__ inline void split1(float x, u16& h, u16& l) {
    unsigned u = __float_as_uint(x);
    h = (u16)(u >> 16);
    float hf = __uint_as_float((u >> 16) << 16);
    l = (u16)(__float_as_uint(x - hf) >> 16);
}
__device__ inline void split8v(float4 v0, float4 v1, s16x8& h, s16x8& l) {
    float x[8] = {v0.x,v0.y,v0.z,v0.w,v1.x,v1.y,v1.z,v1.w};
    #pragma unroll
    for (int j = 0; j < 8; ++j) {
        u16 hh, ll; split1(x[j], hh, ll);
        h[j] = (short)hh; l[j] = (short)ll;
    }
}

// ---------------- Kernel 1: dec_proj[b][n] = dh[b]·Wa_w[:,n] + Wa_b[n] + Ua_b[n]
__global__ void dec_proj_kernel(const float* __restrict__ dh,
                                const float* __restrict__ Wa_w,
                                const float* __restrict__ Wa_b,
                                const float* __restrict__ Ua_b,
                                float* __restrict__ dec_proj) {
    __shared__ float sdh[HH];
    const int b   = blockIdx.x;
    const int nq  = blockIdx.y;           // 0..3
    const int tid = threadIdx.x;          // 256
    for (int i = tid; i < HH; i += 256) sdh[i] = dh[b*HH + i];
    __syncthreads();
    const int n = nq*256 + tid;
    float acc = Wa_b[n] + Ua_b[n];
    for (int k = 0; k < HH; ++k)
        acc = fmaf(sdh[k], Wa_w[(size_t)k*HH + n], acc);
    dec_proj[b*HH + n] = acc;
}

// ---------------- Kernel 2: Ua [K][N] -> B_pre frag-linear split-bf16 image
// (r5/r11-verified 16x16 image)
// B_pre[(nch*NT+kt)*16384 + plane*8192 + f*512 + (c*16+lr)*8 + j]
//   n = nch*256 + f*16 + lr ; k = kt*32 + c*8 + j ; plane 0=hi,1=lo
__global__ void transpose_convert_kernel(const float* __restrict__ Ua,
                                         u16* __restrict__ B_pre) {
    __shared__ u16 shh[64][72], shl[64][72];
    const int nb = blockIdx.x * 64, kb = blockIdx.y * 64;
    const int tid = threadIdx.x;          // 256
    const int kl = tid >> 4, nl4 = (tid & 15) * 4;
    #pragma unroll
    for (int q = 0; q < 4; ++q) {
        const int k = kl + q*16;
        float4 v = *(const float4*)&Ua[(size_t)(kb + k)*HH + nb + nl4];
        float x[4] = {v.x, v.y, v.z, v.w};
        #pragma unroll
        for (int j = 0; j < 4; ++j) {
            u16 hh, ll; split1(x[j], hh, ll);
            shh[k][nl4 + j] = hh; shl[k][nl4 + j] = ll;
        }
    }
    __syncthreads();
    const int nl = tid >> 3, kc8 = (tid & 7) * 8;
    #pragma unroll
    for (int q = 0; q < 2; ++q) {
        const int n = nb + nl + q*32;
        const int kglob = kb + kc8;
        s16x8 hv, lv;
        #pragma unroll
        for (int j = 0; j < 8; ++j) {
            hv[j] = (short)shh[kc8 + j][nl + q*32];
            lv[j] = (short)shl[kc8 + j][nl + q*32];
        }
        const int nchI = n >> 8, fI = (n >> 4) & 15, lrI = n & 15;
        const int ktI = kglob >> 5, cI = (kglob >> 3) & 3;
        const size_t base = (size_t)(nchI*NT + ktI) * BTILE;
        const size_t idxH = base + fI*512 + (cI*16 + lrI)*8;
        *(s16x8*)&B_pre[idxH]        = hv;
        *(s16x8*)&B_pre[idxH + 8192] = lv;
    }
}

// ---------------- Kernel 3: 4-phase (m201-style) split-bf16 3-product GEMM
// BM=256, 8 waves (2m x 4n), per-wave 128x64, acc[8][4]. A-only LDS (64KB
// dbuf), write-linear staging + frag-linear reads (0-conflict, r16-verified).
// B double-buffered in regs, direct from L2 (r17-verified path).
// Per K-tile, 4 phases over m-quads; each phase:
//   {4x ds_read A-quad(p) ; one stage step ; s_barrier ; lgkmcnt(0)+sched ;
//    setprio(1) 24 MFMA setprio(0) ; s_barrier}
// Stage steps: p0 readB(j+1)->Bnext (8 gl loads), p1 writeA(cb^1) (a-regs
// loaded 1 tile ago -> counted vmcnt ~free), p2 loadA(j+2). NO vmcnt(0) in
// the loop (T4): every global load spans >=3 phases before its wait.
// Ledger: buf cb^1 written only in p1 of tile j; each wave's ds_writes are
// drained by its p2 lgkmcnt(0); p2's end barrier orders all waves => buf
// published long before tile j+1 p0 reads it. B/A-reg WARs are in-wave.
__global__ __launch_bounds__(THREADS, 2)
void gemm_8p_kernel(const float* __restrict__ A,        // enc [M, K] fp32
                    const u16* __restrict__ B_pre,      // frag-linear split image
                    const float* __restrict__ dec_proj, // [B, H] (biases folded)
                    const float* __restrict__ Va_w,     // [H]
                    float* __restrict__ partials)       // [M, 16]
{
    __shared__ __align__(16) u16 AhS[2][BM*BK];   // 2 x 16KB
    __shared__ __align__(16) u16 AlS[2][BM*BK];   // 2 x 16KB

    // XCD-chunked bijective swizzle: 1024 blocks, 128 per XCD; nch fastest.
    const int bid = blockIdx.x;
    const int wg  = (bid & 7) * 128 + (bid >> 3);
    const int nch = wg & 3;
    const int mt  = wg >> 2;
    const int m0  = mt * BM, n0 = nch * BN;

    const int tid = threadIdx.x, lane = tid & 63, wid = tid >> 6;
    const int wm = wid >> 2, wn = wid & 3;    // 2 x 4 waves, per-wave 128x64
    const int lr = lane & 15, lk = lane >> 4;

    // A staging: elems e0=tid, e1=tid+512; eid -> frag=eid>>6 (0..15),
    // chunk=(eid>>4)&3, row=eid&15. LDS writes at tid*8 / tid*8+4096
    // (block-linear, 0-conflict); frag read at f*512+lane*8 (0-conflict).
    const int e0 = tid, e1 = tid + 512;
    const float* Ab0 = A + (size_t)(m0 + (e0>>6)*16 + (e0&15))*HH + ((e0>>4)&3)*8;
    const float* Ab1 = A + (size_t)(m0 + (e1>>6)*16 + (e1&15))*HH + ((e1>>4)&3)*8;
    const int aw0 = tid*8, aw1 = tid*8 + 4096;   // u16 units
    // B direct-from-global base: wave reads its 4 frag pairs (1KB each)
    const u16* Bt = B_pre + (size_t)nch*NT*BTILE + (wn*4)*512 + lane*8;

    f32x4 acc[8][4];
    #pragma unroll
    for (int i = 0; i < 8; ++i)
        #pragma unroll
        for (int j = 0; j < 4; ++j) acc[i][j] = (f32x4){0.f,0.f,0.f,0.f};

    s16x8 bhA[4], blA[4], bhB[4], blB[4];   // B double buffer (64 VGPR)
    float4 a0_, a1_, a2_, a3_;              // A staging regs (16 VGPR)

    auto loadA = [&](int kt) {
        const float* p0 = Ab0 + kt*BK;
        const float* p1 = Ab1 + kt*BK;
        a0_ = *(const float4*)(p0 + 0);
        a1_ = *(const float4*)(p0 + 4);
        a2_ = *(const float4*)(p1 + 0);
        a3_ = *(const float4*)(p1 + 4);
    };
    auto writeA = [&](int db) {
        s16x8 h, l;
        split8v(a0_, a1_, h, l);
        *(s16x8*)&AhS[db][aw0] = h; *(s16x8*)&AlS[db][aw0] = l;
        split8v(a2_, a3_, h, l);
        *(s16x8*)&AhS[db][aw1] = h; *(s16x8*)&AlS[db][aw1] = l;
    };
    auto readB = [&](int kt, s16x8 (&bh)[4], s16x8 (&bl)[4]) {
        const u16* p = Bt + (size_t)kt*BTILE;
        #pragma unroll
        for (int q = 0; q < 4; ++q) {
            bh[q] = *(const s16x8*)(p + q*512);
            bl[q] = *(const s16x8*)(p + 8192 + q*512);
        }
    };

    // one tile = 4 phases; Bcur used by all MFMA, Bnext filled in phase 0
    auto tile = [&](int j, s16x8 (&Bch)[4], s16x8 (&Bcl)[4],
                           s16x8 (&Bnh)[4], s16x8 (&Bnl)[4]) {
        const int  cb = j & 1;
        const bool hn = (j + 1 < NT);
        #pragma unroll
        for (int p = 0; p < 4; ++p) {
            // ds_read this quad's A frags (issued before barrier)
            const int f0 = (wm*8 + p*2)*512 + lane*8;
            s16x8 ah0 = *(const s16x8*)&AhS[cb][f0];
            s16x8 al0 = *(const s16x8*)&AlS[cb][f0];
            s16x8 ah1 = *(const s16x8*)&AhS[cb][f0 + 512];
            s16x8 al1 = *(const s16x8*)&AlS[cb][f0 + 512];
            // one stage step per phase
            if (p == 0 && hn) readB(j + 1, Bnh, Bnl);
            if (p == 1 && hn) writeA(cb ^ 1);           // a-regs = A(j+1)
            if (p == 2 && j + 2 < NT) loadA(j + 2);
            __builtin_amdgcn_s_barrier();
            asm volatile("s_waitcnt lgkmcnt(0)" ::: "memory");
            __builtin_amdgcn_sched_barrier(0);
            __builtin_amdgcn_s_setprio(1);
            #pragma unroll
            for (int q = 0; q < 4; ++q) {
                f32x4 c0 = acc[p*2 + 0][q];
                c0 = __builtin_amdgcn_mfma_f32_16x16x32_bf16(ah0, Bch[q], c0, 0, 0, 0);
                c0 = __builtin_amdgcn_mfma_f32_16x16x32_bf16(ah0, Bcl[q], c0, 0, 0, 0);
                c0 = __builtin_amdgcn_mfma_f32_16x16x32_bf16(al0, Bch[q], c0, 0, 0, 0);
                acc[p*2 + 0][q] = c0;
                f32x4 c1 = acc[p*2 + 1][q];
                c1 = __builtin_amdgcn_mfma_f32_16x16x32_bf16(ah1, Bch[q], c1, 0, 0, 0);
                c1 = __builtin_amdgcn_mfma_f32_16x16x32_bf16(ah1, Bcl[q], c1, 0, 0, 0);
                c1 = __builtin_amdgcn_mfma_f32_16x16x32_bf16(al1, Bch[q], c1, 0, 0, 0);
                acc[p*2 + 1][q] = c1;
            }
            __builtin_amdgcn_s_setprio(0);
            __builtin_amdgcn_s_barrier();
        }
    };

    // prologue: stage A(0) into buf 0, B(0) into regs; one full drain
    loadA(0);
    writeA(0);
    readB(0, bhA, blA);
    __syncthreads();
    loadA(1);   // A(1) regs held until tile 0 phase 1

    for (int j2 = 0; j2 < NT; j2 += 2) {     // unroll-2: static B buffers
        tile(j2,     bhA, blA, bhB, blB);
        tile(j2 + 1, bhB, blB, bhA, blA);
    }

    // epilogue: rowsum over this wave's 64 n-cols of Va[n]*tanh(C+dp[n])
    // 16x16 C layout (verified): col=lane&15, row=(lane>>4)*4+reg
    const int bidx = m0 >> 11;            // batch index (2048 rows per batch)
    float dp[4], va[4];
    #pragma unroll
    for (int j = 0; j < 4; ++j) {
        const int n = n0 + wn*64 + j*16 + lr;
        dp[j] = dec_proj[bidx*HH + n];
        va[j] = Va_w[n];
    }
    #pragma unroll
    for (int f = 0; f < 8; ++f) {
        #pragma unroll
        for (int r = 0; r < 4; ++r) {
            float s = 0.f;
            #pragma unroll
            for (int j = 0; j < 4; ++j)
                s += va[j] * tanhf(acc[f][j][r] + dp[j]);
            s += __shfl_xor(s, 1, 64);
            s += __shfl_xor(s, 2, 64);
            s += __shfl_xor(s, 4, 64);
            s += __shfl_xor(s, 8, 64);
            if (lr == 0) {
                const int m = m0 + wm*128 + f*16 + lk*4 + r;
                partials[(size_t)m*16 + nch*4 + wn] = s;
            }
        }
    }
}

// ---------------- Kernel 4: sum 16 partials + Va_b, mask, softmax over S
__global__ void softmax_kernel(const float* __restrict__ partials,
                               const int* __restrict__ mask,
                               const float* __restrict__ vb_ptr,
                               float* __restrict__ out)
{
    const int b   = blockIdx.x;
    const int tid = threadIdx.x;   // 256, each handles 8 s-positions
    __shared__ float sred[8];
    const float vb = vb_ptr[0];
    float sc[8];
    float mymax = -INFINITY;
    #pragma unroll
    for (int i = 0; i < 8; ++i) {
        const int s = i*256 + tid;
        const float4* p = (const float4*)&partials[((size_t)b*SS + s)*16];
        const float4 x = p[0], y = p[1], z = p[2], w = p[3];
        float v = (((x.x+x.y)+(x.z+x.w)) + ((y.x+y.y)+(y.z+y.w)))
                + (((z.x+z.y)+(z.z+z.w)) + ((w.x+w.y)+(w.z+w.w))) + vb;
        if (mask[b*SS + s] == 0) v = -1e9f;
        sc[i] = v;
        mymax = fmaxf(mymax, v);
    }
    #pragma unroll
    for (int off = 1; off < 64; off <<= 1)
        mymax = fmaxf(mymax, __shfl_xor(mymax, off, 64));
    const int wave = tid >> 6, lane = tid & 63;
    if (lane == 0) sred[wave] = mymax;
    __syncthreads();
    const float bmax = fmaxf(fmaxf(sred[0], sred[1]), fmaxf(sred[2], sred[3]));
    float ex[8], mysum = 0.f;
    #pragma unroll
    for (int i = 0; i < 8; ++i) {
        ex[i] = __expf(sc[i] - bmax);
        mysum += ex[i];
    }
    #pragma unroll
    for (int off = 1; off < 64; off <<= 1)
        mysum += __shfl_xor(mysum, off, 64);
    if (lane == 0) sred[4 + wave] = mysum;
    __syncthreads();
    const float inv = 1.f / (sred[4] + sred[5] + sred[6] + sred[7]);
    #pragma unroll
    for (int i = 0; i < 8; ++i)
        out[(size_t)b*SS + i*256 + tid] = ex[i] * inv;
}

extern "C" void kernel_launch(void* const* d_in, const int* in_sizes, int n_in,
                              void* d_out, int out_size, void* d_ws, size_t ws_size,
                              hipStream_t stream) {
    const float* dh   = (const float*)d_in[0];
    const float* enc  = (const float*)d_in[1];
    const int*   mask = (const int*)d_in[2];
    const float* Wa_w = (const float*)d_in[3];
    const float* Wa_b = (const float*)d_in[4];
    const float* Ua_w = (const float*)d_in[5];
    const float* Ua_b = (const float*)d_in[6];
    const float* Va_w = (const float*)d_in[7];
    const float* Va_b = (const float*)d_in[8];
    float* out = (float*)d_out;

    float* dec_proj = (float*)d_ws;                       // [B,H]    128 KB
    float* partials = dec_proj + BB*HH;                   // [M,16]   4 MB
    u16*   B_pre    = (u16*)(partials + (size_t)MT*16);   // frag-linear, 4 MB

    dec_proj_kernel<<<dim3(BB, 4), 256, 0, stream>>>(dh, Wa_w, Wa_b, Ua_b, dec_proj);
    transpose_convert_kernel<<<dim3(HH/64, HH/64), 256, 0, stream>>>(Ua_w, B_pre);
    gemm_8p_kernel<<<(MT/BM)*NCH, THREADS, 0, stream>>>(enc, B_pre, dec_proj, Va_w, partials);
    softmax_kernel<<<BB, 256, 0, stream>>>(partials, mask, Va_b, out);
}

// Round 21
// 389.717 us; speedup vs baseline: 1.4230x; 1.4230x over previous
//
#include <hip/hip_runtime.h>
#include <math.h>

#define BB 32
#define SS 2048
#define HH 1024
#define MT (BB*SS)      // 65536 rows

#define BM 128
#define BN 256
#define BK 32           // fp32 k per tile (hi/lo bf16 planes)
#define NT (HH/BK)      // 32 k-tiles
#define NCH (HH/BN)     // 4 n-chunks
#define THREADS 512     // 8 waves (2m x 4n), per-wave 64x64; 2 blocks/CU
// B_pre per (nch,kt) tile: 2 planes x 16 frags x 512 u16 = 16384 u16 (32KB)
#define BTILE 16384

typedef float  f32x4 __attribute__((ext_vector_type(4)));
typedef short  s16x8 __attribute__((ext_vector_type(8)));
typedef unsigned short u16;

// truncation split: x ~= hi + lo, |x - hi - lo| <= 2^-16 |x|
__device__ inline void split1(float x, u16& h, u16& l) {
    unsigned u = __float_as_uint(x);
    h = (u16)(u >> 16);
    float hf = __uint_as_float((u >> 16) << 16);
    l = (u16)(__float_as_uint(x - hf) >> 16);
}
__device__ inline void split8v(float4 v0, float4 v1, s16x8& h, s16x8& l) {
    float x[8] = {v0.x,v0.y,v0.z,v0.w,v1.x,v1.y,v1.z,v1.w};
    #pragma unroll
    for (int j = 0; j < 8; ++j) {
        u16 hh, ll; split1(x[j], hh, ll);
        h[j] = (short)hh; l[j] = (short)ll;
    }
}

// ---------------- Kernel 1: dec_proj[b][n] = dh[b]·Wa_w[:,n] + Wa_b[n] + Ua_b[n]
// 256 blocks (full CU coverage; was 128) x 128 threads; 4 independent
// accumulators break the 1024-long dependent fmaf chain (4096 -> ~1024 cyc).
__global__ void dec_proj_kernel(const float* __restrict__ dh,
                                const float* __restrict__ Wa_w,
                                const float* __restrict__ Wa_b,
                                const float* __restrict__ Ua_b,
                                float* __restrict__ dec_proj) {
    __shared__ float sdh[HH];
    const int b   = blockIdx.x;
    const int nq  = blockIdx.y;           // 0..7
    const int tid = threadIdx.x;          // 128
    #pragma unroll
    for (int i = 0; i < 2; ++i)
        *(float4*)&sdh[(tid + i*128)*4] =
            *(const float4*)&dh[b*HH + (tid + i*128)*4];
    __syncthreads();
    const int n = nq*128 + tid;
    float a0 = 0.f, a1 = 0.f, a2 = 0.f, a3 = 0.f;
    for (int k = 0; k < HH; k += 4) {
        a0 = fmaf(sdh[k+0], Wa_w[(size_t)(k+0)*HH + n], a0);
        a1 = fmaf(sdh[k+1], Wa_w[(size_t)(k+1)*HH + n], a1);
        a2 = fmaf(sdh[k+2], Wa_w[(size_t)(k+2)*HH + n], a2);
        a3 = fmaf(sdh[k+3], Wa_w[(size_t)(k+3)*HH + n], a3);
    }
    dec_proj[b*HH + n] = ((a0 + a1) + (a2 + a3)) + Wa_b[n] + Ua_b[n];
}

// ---------------- Kernel 2: Ua [K][N] -> B_pre frag-linear split-bf16 image
// (r5/r11-verified 16x16 image)
// B_pre[(nch*NT+kt)*16384 + plane*8192 + f*512 + (c*16+lr)*8 + j]
//   n = nch*256 + f*16 + lr ; k = kt*32 + c*8 + j ; plane 0=hi,1=lo
__global__ void transpose_convert_kernel(const float* __restrict__ Ua,
                                         u16* __restrict__ B_pre) {
    __shared__ u16 shh[64][72], shl[64][72];
    const int nb = blockIdx.x * 64, kb = blockIdx.y * 64;
    const int tid = threadIdx.x;          // 256
    const int kl = tid >> 4, nl4 = (tid & 15) * 4;
    #pragma unroll
    for (int q = 0; q < 4; ++q) {
        const int k = kl + q*16;
        float4 v = *(const float4*)&Ua[(size_t)(kb + k)*HH + nb + nl4];
        float x[4] = {v.x, v.y, v.z, v.w};
        #pragma unroll
        for (int j = 0; j < 4; ++j) {
            u16 hh, ll; split1(x[j], hh, ll);
            shh[k][nl4 + j] = hh; shl[k][nl4 + j] = ll;
        }
    }
    __syncthreads();
    const int nl = tid >> 3, kc8 = (tid & 7) * 8;
    #pragma unroll
    for (int q = 0; q < 2; ++q) {
        const int n = nb + nl + q*32;
        const int kglob = kb + kc8;
        s16x8 hv, lv;
        #pragma unroll
        for (int j = 0; j < 8; ++j) {
            hv[j] = (short)shh[kc8 + j][nl + q*32];
            lv[j] = (short)shl[kc8 + j][nl + q*32];
        }
        const int nchI = n >> 8, fI = (n >> 4) & 15, lrI = n & 15;
        const int ktI = kglob >> 5, cI = (kglob >> 3) & 3;
        const size_t base = (size_t)(nchI*NT + ktI) * BTILE;
        const size_t idxH = base + fI*512 + (cI*16 + lrI)*8;
        *(s16x8*)&B_pre[idxH]        = hv;
        *(s16x8*)&B_pre[idxH + 8192] = lv;
    }
}

// ---------------- Kernel 3: split-bf16 3-product MFMA GEMM, 16x16x32
// r19 EXACTLY (best measured: 393.7us total, GEMM ~1057 TF, MfmaUtil ~45%).
// Free-run structure: one raw barrier per tile (lgkmcnt(0) only, NO vmcnt
// drain -- T4), B direct-from-L2 prefetched one tile ahead, A reg-staged
// (split needs VALU) with write-linear 0-conflict LDS maps, 2 blocks/CU.
// Lockstep phase ports (r4/r12/r20) all regressed: the fp32-split forces
// reg-staging (no global_load_lds), so per-phase stage steps serialize
// barrier-synced waves. This coarse schedule is the verified optimum.
__global__ __launch_bounds__(THREADS, 4)
void gemm_fr_kernel(const float* __restrict__ A,        // enc [M, K] fp32
                    const u16* __restrict__ B_pre,      // frag-linear split image
                    const float* __restrict__ dec_proj, // [B, H] (biases folded)
                    const float* __restrict__ Va_w,     // [H]
                    float* __restrict__ partials)       // [M, 16]
{
    __shared__ __align__(16) u16 AhS[2][BM*BK];   // 2 x 8KB
    __shared__ __align__(16) u16 AlS[2][BM*BK];   // 2 x 8KB

    // XCD-chunked bijective swizzle: 2048 blocks, 256 per XCD;
    // nch fastest -> 4 consecutive blocks share each A panel via L2.
    const int bid = blockIdx.x;
    const int wg  = (bid & 7) * 256 + (bid >> 3);
    const int nch = wg & 3;
    const int mt  = wg >> 2;                  // 0..511
    const int m0  = mt * BM, n0 = nch * BN;

    const int tid = threadIdx.x, lane = tid & 63, wid = tid >> 6;
    const int wm = wid >> 2, wn = wid & 3;    // 2 x 4 waves, per-wave 64x64
    const int lr = lane & 15, lk = lane >> 4;

    // A staging (write-linear map): tid -> frag=tid>>6 (0..7),
    // chunk=(tid>>4)&3, row=tid&15; LDS write at tid*16B (0-conflict);
    // frag read at f*512+lane*8 (1KB linear, 0-conflict).
    const float* Ab = A + (size_t)(m0 + (tid>>6)*16 + (tid&15))*HH + ((tid>>4)&3)*8;
    const int awoff = tid*8;   // u16 units
    // B direct-from-global base: wave reads its 4 frag pairs (1KB each)
    const u16* Bt = B_pre + (size_t)nch*NT*BTILE + (wn*4)*512 + lane*8;

    f32x4 acc[4][4];
    #pragma unroll
    for (int i = 0; i < 4; ++i)
        #pragma unroll
        for (int j = 0; j < 4; ++j) acc[i][j] = (f32x4){0.f,0.f,0.f,0.f};

    s16x8  bh[4], bl[4];      // B frags; prefetched one tile ahead (32 VGPR)
    float4 a0_, a1_;          // A staging regs (8 VGPR)

    auto loadA = [&](int kt) {
        const float* p = Ab + kt*BK;
        a0_ = *(const float4*)(p + 0);
        a1_ = *(const float4*)(p + 4);
    };
    auto writeA = [&](int db) {
        s16x8 h, l;
        split8v(a0_, a1_, h, l);
        *(s16x8*)&AhS[db][awoff] = h;
        *(s16x8*)&AlS[db][awoff] = l;
    };
    auto readB = [&](int kt) {
        const u16* p = Bt + (size_t)kt*BTILE;
        #pragma unroll
        for (int j = 0; j < 4; ++j) {
            bh[j] = *(const s16x8*)(p + j*512);
            bl[j] = *(const s16x8*)(p + 8192 + j*512);
        }
    };

    // prologue: stage A tile 0 into buf 0; B(0) into regs
    loadA(0);
    writeA(0);
    readB(0);
    __syncthreads();            // one full drain outside the loop is fine
    loadA(1);                   // A(1) regs held through iter 0

    for (int j = 0; j < NT; ++j) {
        const int cb = j & 1;
        const bool hn = (j + 1 < NT);

        #pragma unroll
        for (int f = 0; f < 4; ++f) {
            const int o = (wm*4 + f)*512 + lane*8;   // 1KB linear frag read
            const s16x8 ah = *(const s16x8*)&AhS[cb][o];
            const s16x8 al = *(const s16x8*)&AlS[cb][o];
            __builtin_amdgcn_s_setprio(1);
            #pragma unroll
            for (int q = 0; q < 4; ++q) {
                f32x4 c = acc[f][q];
                c = __builtin_amdgcn_mfma_f32_16x16x32_bf16(ah, bh[q], c, 0, 0, 0);
                c = __builtin_amdgcn_mfma_f32_16x16x32_bf16(ah, bl[q], c, 0, 0, 0);
                c = __builtin_amdgcn_mfma_f32_16x16x32_bf16(al, bh[q], c, 0, 0, 0);
                acc[f][q] = c;
            }
            __builtin_amdgcn_s_setprio(0);
        }
        // tail staging: B prefetch first (WAR on bh/bl is free), then A
        if (hn) {
            readB(j + 1);                          // spans tail+barrier -> hidden
            writeA(cb ^ 1);                        // waits vmcnt(8): a-regs old
            loadA(j + 2 < NT ? j + 2 : j + 1);     // stays in flight past barrier
        }
        // raw barrier: publish ds_writes only; NO vmcnt drain (T4)
        asm volatile("s_waitcnt lgkmcnt(0)" ::: "memory");
        __builtin_amdgcn_sched_barrier(0);
        __builtin_amdgcn_s_barrier();
        __builtin_amdgcn_sched_barrier(0);
    }

    // epilogue: rowsum over this wave's 64 n-cols of Va[n]*tanh(C+dp[n])
    // 16x16 C layout (verified): col=lane&15, row=(lane>>4)*4+reg
    const int bidx = m0 >> 11;            // batch index (2048 rows per batch)
    float dp[4], va[4];
    #pragma unroll
    for (int j = 0; j < 4; ++j) {
        const int n = n0 + wn*64 + j*16 + lr;
        dp[j] = dec_proj[bidx*HH + n];
        va[j] = Va_w[n];
    }
    #pragma unroll
    for (int f = 0; f < 4; ++f) {
        #pragma unroll
        for (int r = 0; r < 4; ++r) {
            float s = 0.f;
            #pragma unroll
            for (int j = 0; j < 4; ++j)
                s += va[j] * tanhf(acc[f][j][r] + dp[j]);
            s += __shfl_xor(s, 1, 64);
            s += __shfl_xor(s, 2, 64);
            s += __shfl_xor(s, 4, 64);
            s += __shfl_xor(s, 8, 64);
            if (lr == 0) {
                const int m = m0 + wm*64 + f*16 + lk*4 + r;
                partials[(size_t)m*16 + nch*4 + wn] = s;
            }
        }
    }
}

// ---------------- Kernel 4: sum 16 partials + Va_b, mask, softmax over S
__global__ void softmax_kernel(const float* __restrict__ partials,
                               const int* __restrict__ mask,
                               const float* __restrict__ vb_ptr,
                               float* __restrict__ out)
{
    const int b   = blockIdx.x;
    const int tid = threadIdx.x;   // 256, each handles 8 s-positions
    __shared__ float sred[8];
    const float vb = vb_ptr[0];
    float sc[8];
    float mymax = -INFINITY;
    #pragma unroll
    for (int i = 0; i < 8; ++i) {
        const int s = i*256 + tid;
        const float4* p = (const float4*)&partials[((size_t)b*SS + s)*16];
        const float4 x = p[0], y = p[1], z = p[2], w = p[3];
        float v = (((x.x+x.y)+(x.z+x.w)) + ((y.x+y.y)+(y.z+y.w)))
                + (((z.x+z.y)+(z.z+z.w)) + ((w.x+w.y)+(w.z+w.w))) + vb;
        if (mask[b*SS + s] == 0) v = -1e9f;
        sc[i] = v;
        mymax = fmaxf(mymax, v);
    }
    #pragma unroll
    for (int off = 1; off < 64; off <<= 1)
        mymax = fmaxf(mymax, __shfl_xor(mymax, off, 64));
    const int wave = tid >> 6, lane = tid & 63;
    if (lane == 0) sred[wave] = mymax;
    __syncthreads();
    const float bmax = fmaxf(fmaxf(sred[0], sred[1]), fmaxf(sred[2], sred[3]));
    float ex[8], mysum = 0.f;
    #pragma unroll
    for (int i = 0; i < 8; ++i) {
        ex[i] = __expf(sc[i] - bmax);
        mysum += ex[i];
    }
    #pragma unroll
    for (int off = 1; off < 64; off <<= 1)
        mysum += __shfl_xor(mysum, off, 64);
    if (lane == 0) sred[4 + wave] = mysum;
    __syncthreads();
    const float inv = 1.f / (sred[4] + sred[5] + sred[6] + sred[7]);
    #pragma unroll
    for (int i = 0; i < 8; ++i)
        out[(size_t)b*SS + i*256 + tid] = ex[i] * inv;
}

extern "C" void kernel_launch(void* const* d_in, const int* in_sizes, int n_in,
                              void* d_out, int out_size, void* d_ws, size_t ws_size,
                              hipStream_t stream) {
    const float* dh   = (const float*)d_in[0];
    const float* enc  = (const float*)d_in[1];
    const int*   mask = (const int*)d_in[2];
    const float* Wa_w = (const float*)d_in[3];
    const float* Wa_b = (const float*)d_in[4];
    const float* Ua_w = (const float*)d_in[5];
    const float* Ua_b = (const float*)d_in[6];
    const float* Va_w = (const float*)d_in[7];
    const float* Va_b = (const float*)d_in[8];
    float* out = (float*)d_out;

    float* dec_proj = (float*)d_ws;                       // [B,H]    128 KB
    float* partials = dec_proj + BB*HH;                   // [M,16]   4 MB
    u16*   B_pre    = (u16*)(partials + (size_t)MT*16);   // frag-linear, 4 MB

    dec_proj_kernel<<<dim3(BB, 8), 128, 0, stream>>>(dh, Wa_w, Wa_b, Ua_b, dec_proj);
    transpose_convert_kernel<<<dim3(HH/64, HH/64), 256, 0, stream>>>(Ua_w, B_pre);
    gemm_fr_kernel<<<(MT/BM)*NCH, THREADS, 0, stream>>>(enc, B_pre, dec_proj, Va_w, partials);
    softmax_kernel<<<BB, 256, 0, stream>>>(partials, mask, Va_b, out);
}